// Round 5
// baseline (248.568 us; speedup 1.0000x reference)
//
#include <hip/hip_runtime.h>
#include <stdint.h>

#define KPS 512
#define NBOX 1536
#define NBINS 1024

// scale cell counts: 32*H*H*3
#define S13 16224
#define S26 64896
#define S52 259584
#define TOTCELL 340704

__device__ __forceinline__ uint32_t f2u(float x){ union{float f;uint32_t u;}v; v.f=x; return v.u; }
__device__ __forceinline__ float u2f(uint32_t x){ union{float f;uint32_t u;}v; v.u=x; return v.f; }

__device__ __forceinline__ int binOf(float s){
    int b = (int)((s - 0.6f) * 2560.0f);    // 1024 bins over (0.6, 1.0)
    if (b < 0) b = 0;
    if (b > NBINS-1) b = NBINS-1;
    return b;
}

// cnt layout: [0..2] Nsel, [3..5] aboveCnt, [6..8] stashCnt, [9..11] cutoff bin B
__global__ void k_init(int* hist, int* cnt){
    int id = blockIdx.x*256 + threadIdx.x;
    if (id < 3*NBINS) hist[id] = 0;
    if (id < 32) cnt[id] = 0;
}

// Score pass: 4-byte sigmoid-bits per cell (0 if below threshold) + global
// histogram atomics (sparse: only ~1/3 of cells pass threshold, spread over
// 1024 bins -> negligible contention; R2-proven pattern).
__global__ void k_score(const float* __restrict__ o13, const float* __restrict__ o26,
                        const float* __restrict__ o52,
                        unsigned* __restrict__ scr, int* __restrict__ hist){
    int id = blockIdx.x*256 + threadIdx.x;
    if (id >= TOTCELL) return;
    int scale, idl, H;
    const float* src;
    if (id < S13)            { scale=0; idl=id;            H=13; src=o13; }
    else if (id < S13+S26)   { scale=1; idl=id-S13;        H=26; src=o26; }
    else                     { scale=2; idl=id-(S13+S26);  H=52; src=o52; }
    int HW = H*H;
    // plane-major thread mapping for coalescing: idl = p*HW + hw, p = n*3 + a
    int p  = idl / HW;
    int hw = idl - p*HW;
    int n  = p / 3;
    int a  = p - n*3;
    float x = src[(size_t)(n*255 + a*85)*HW + hw];
    float s = (float)(1.0 / (1.0 + exp(-(double)x)));   // correctly-rounded f32 sigmoid
    if (s > 0.6f){
        scr[id] = f2u(s);
        atomicAdd(&hist[scale*NBINS + binOf(s)], 1);
    } else {
        scr[id] = 0u;
    }
}

// Suffix scan of the per-scale histogram -> cutoff bin B (cnt[9+s]).
// B = -1 means "fewer than KPS candidates total; take everything".
__global__ void __launch_bounds__(1024) k_cutoff(const int* __restrict__ hist, int* __restrict__ cnt){
    int s = blockIdx.x, t = threadIdx.x;
    __shared__ int suf[NBINS];
    int h = hist[s*NBINS + t];
    suf[t] = h; __syncthreads();
    for (int d=1; d<NBINS; d<<=1){
        int v = (t+d < NBINS) ? suf[t+d] : 0;
        __syncthreads();
        suf[t] += v;
        __syncthreads();
    }
    int total = suf[0];
    int A = (t < NBINS-1) ? suf[t+1] : 0;   // count strictly above bin t
    if (t == 0 && total < KPS) cnt[9+s] = -1;
    if (A < KPS && A + h >= KPS) cnt[9+s] = t;   // exactly one writer when total>=KPS
}

// Grid-wide partition: uint4 over scr, reconstruct keys only for candidates
// with bin >= B (~1.3% density), append to global above/stash lists via
// plain device atomics (order nondeterministic; finalize rank-sort makes the
// final sel order deterministic since keys are unique).
__global__ void k_classify(const unsigned* __restrict__ scr, int* __restrict__ cnt,
                           unsigned long long* __restrict__ above, unsigned long long* __restrict__ stash){
    int tid = blockIdx.x*256 + threadIdx.x;     // uint4 index
    if (tid >= TOTCELL/4) return;
    const uint4* v4 = reinterpret_cast<const uint4*>(scr);
    uint4 u = v4[tid];
    if (!(u.x | u.y | u.z | u.w)) return;
    int id0 = tid*4;
    int scale, off, H;                          // scale boundaries divisible by 4
    if (id0 < S13)           { scale=0; off=0;       H=13; }
    else if (id0 < S13+S26)  { scale=1; off=S13;     H=26; }
    else                     { scale=2; off=S13+S26; H=52; }
    int HW = H*H;
    int B = cnt[9+scale];
    #pragma unroll
    for (int c = 0; c < 4; c++){
        unsigned sb = (c==0)?u.x:(c==1)?u.y:(c==2)?u.z:u.w;
        if (!sb) continue;
        int bin = binOf(u2f(sb));
        if (bin < B) continue;
        int idx = id0 + c - off;                // in-scale linear id
        int p  = idx / HW;
        int hw = idx - p*HW;
        int n  = p / 3;
        int a  = p - n*3;
        int cidx = (n*HW + hw)*3 + a;
        unsigned long long key = ((unsigned long long)sb << 20)
            | ((unsigned long long)(2-scale) << 18)
            | (unsigned long long)(262143 - cidx);
        if (bin > B){
            int pos = atomicAdd(&cnt[3+scale], 1);   // < 512 by cutoff definition
            if (pos < KPS) above[scale*KPS + pos] = key;
        } else {
            int pos = atomicAdd(&cnt[6+scale], 1);
            if (pos < 1024) stash[scale*1024 + pos] = key;   // same clamp as before
        }
    }
}

// Rank-sort the above∪stash union per scale (keys unique & nonzero):
// rank = #{greater}. Above-keys all outrank stash-keys (bin monotone in the
// key's top bits), so top-Nsel == above + top-m(stash) — identical selection
// to the verified R2/R4 pipelines. Writes sel sorted desc + zero sentinels.
__global__ void __launch_bounds__(1024) k_finalize(int* __restrict__ cnt,
                           const unsigned long long* __restrict__ above,
                           const unsigned long long* __restrict__ stash,
                           unsigned long long* __restrict__ sel){
    int s = blockIdx.x, t = threadIdx.x;
    __shared__ unsigned long long un[1536];     // [0,512) above, [512,1536) stash
    int cA = cnt[3+s];                          // < 512 guaranteed
    int cSk = cnt[6+s]; if (cSk > 1024) cSk = 1024;
    int need = KPS - cA; if (need < 0) need = 0;
    int m = (need < cSk) ? need : cSk;
    int Nsel = cA + m;
    if (t < cA)  un[t] = above[s*KPS + t];
    if (t < cSk) un[512 + t] = stash[s*1024 + t];
    __syncthreads();
    int E = cA + cSk;
    for (int e = t; e < E; e += 1024){
        unsigned long long k = (e < cA) ? un[e] : un[512 + e - cA];
        int rank = 0;
        for (int q = 0; q < cA; q++)  rank += (un[q] > k) ? 1 : 0;
        for (int q = 0; q < cSk; q++) rank += (un[512 + q] > k) ? 1 : 0;
        if (rank < Nsel) sel[s*KPS + rank] = k;
    }
    if (t < KPS && t >= Nsel) sel[s*KPS + t] = 0ull;   // sentinels
    if (t == 0) cnt[s] = Nsel;
}

// Fused decode+merge: stage all sel keys in LDS, compute each box's global rank
// (wave scan + shuffle reduce; keys unique, zeros tie-broken by position),
// decode, and write straight to sboxes[rank]. Block 0 emits analytic vwords.
__global__ void k_decode_merge(const float* __restrict__ o13, const float* __restrict__ o26,
                         const float* __restrict__ o52,
                         const float* __restrict__ a13, const float* __restrict__ a26,
                         const float* __restrict__ a52,
                         const unsigned long long* __restrict__ sel, const int* __restrict__ cnt,
                         float* __restrict__ sboxes, unsigned long long* __restrict__ vwords){
    __shared__ unsigned long long sk[NBOX];
    int t = threadIdx.x;
    for (int r = t; r < NBOX; r += 256) sk[r] = sel[r];
    __syncthreads();
    int wv = t >> 6, lane = t & 63;
    int b = blockIdx.x*4 + wv;
    unsigned long long key = sk[b];
    int pc = 0;
    for (int q = lane; q < NBOX; q += 64){
        unsigned long long kq = sk[q];
        pc += (kq > key || (kq == key && q < b)) ? 1 : 0;
    }
    #pragma unroll
    for (int off = 32; off; off >>= 1) pc += __shfl_xor(pc, off);
    int rank = pc;                       // permutation of [0,NBOX)
    float* row = sboxes + rank*12;
    if ((key >> 20) == 0ull){            // sentinel
        if (lane < 9) row[lane] = 0.f;
    } else {
        int scale = 2 - (int)((key >> 18) & 3ull);
        int cidx  = 262143 - (int)(key & 0x3FFFFull);
        uint32_t sbits = (uint32_t)(key >> 20);
        const float* src; const float* anch; int H; float tt;
        if (scale == 0){ src=o13; anch=a13; H=13; tt=32.f; }
        else if (scale == 1){ src=o26; anch=a26; H=26; tt=16.f; }
        else { src=o52; anch=a52; H=52; tt=8.f; }
        int HW = H*H;
        int a  = cidx % 3;
        int hw = (cidx/3) % HW;
        int n  = cidx / (3*HW);
        int hh = hw / H;
        int ww = hw - hh*H;
        const float* cellbase = src + (size_t)(n*255 + a*85)*HW + hw;
        // argmax over 80 classes, tie -> lowest class index
        float bv = cellbase[(size_t)(5 + lane)*HW];
        int bi = lane;
        if (lane < 16){
            float v2 = cellbase[(size_t)(69 + lane)*HW];
            if (v2 > bv){ bv = v2; bi = 64 + lane; }
        }
        #pragma unroll
        for (int off=32; off; off>>=1){
            float vo = __shfl_xor(bv, off);
            int io = __shfl_xor(bi, off);
            if (vo > bv || (vo == bv && io < bi)){ bv = vo; bi = io; }
        }
        if (lane == 0){
            float v1 = cellbase[(size_t)1*HW];
            float v2 = cellbase[(size_t)2*HW];
            float v3 = cellbase[(size_t)3*HW];
            float v4 = cellbase[(size_t)4*HW];
            float cx = ((float)ww + v1) * tt / 416.0f;
            float cy = ((float)hh + v2) * tt / 416.0f;
            float e3 = (float)exp((double)v3);
            float e4 = (float)exp((double)v4);
            float bw = anch[a*2+0] * e3 / 416.0f;
            float bh = anch[a*2+1] * e4 / 416.0f;
            row[0] = (float)n;  row[1] = cx; row[2] = cy; row[3] = bw; row[4] = bh;
            row[5] = u2f(sbits); row[6] = (float)bi; row[7] = (float)hh; row[8] = (float)ww;
        }
    }
    if (blockIdx.x == 0 && t < 24){
        int nv = cnt[0] + cnt[1] + cnt[2];   // valid keys sort to a contiguous prefix
        int rem = nv - t*64;
        vwords[t] = rem >= 64 ? ~0ull : (rem <= 0 ? 0ull : ((1ull << rem) - 1ull));
    }
}

// Column-sliced suppression matrix: Tcol[i*64 + j] bit c = sup(i, c*64+j).
// Diagonal-tile ROW masks: diagR[i] bit j = sup(i, gi*64+j) where gi = i>>6.
__global__ void k_masks(const float* __restrict__ sboxes, unsigned* __restrict__ Tcol,
                        unsigned long long* __restrict__ diagR){
    int i = blockIdx.x;
    int lane = threadIdx.x;
    int gi = i >> 6;
    float cxi = sboxes[i*12+1], cyi = sboxes[i*12+2], wi = sboxes[i*12+3], hi = sboxes[i*12+4];
    float x1i = cxi - wi/2.0f, y1i = cyi - hi/2.0f, x2i = cxi + wi/2.0f, y2i = cyi + hi/2.0f;
    float ari = fmaxf(x2i-x1i, 0.f) * fmaxf(y2i-y1i, 0.f);
    unsigned colbits = 0u;
    for (int c=0; c<24; c++){
        int j = c*64 + lane;
        float cxj = sboxes[j*12+1], cyj = sboxes[j*12+2], wj = sboxes[j*12+3], hj = sboxes[j*12+4];
        float x1j = cxj - wj/2.0f, y1j = cyj - hj/2.0f, x2j = cxj + wj/2.0f, y2j = cyj + hj/2.0f;
        float arj = fmaxf(x2j-x1j, 0.f) * fmaxf(y2j-y1j, 0.f);
        float ix = fmaxf(0.f, fminf(x2i, x2j) - fmaxf(x1i, x1j));
        float iy = fmaxf(0.f, fminf(y2i, y2j) - fmaxf(y1i, y1j));
        float inter = ix * iy;
        float iou = inter / fmaxf(fminf(ari, arj), 1e-9f);
        bool sb = (iou > 0.7f) && (j > i);
        colbits |= sb ? (1u << c) : 0u;
    }
    Tcol[(size_t)i*64 + lane] = colbits;
    unsigned long long rowbits = __ballot(((colbits >> gi) & 1u) != 0u);
    if (lane == 0) diagR[i] = rowbits;
}

__device__ __forceinline__ unsigned long long readlane64(unsigned long long v, int i){
    unsigned lo = (unsigned)__builtin_amdgcn_readlane((int)(unsigned)v, i);
    unsigned hi = (unsigned)__builtin_amdgcn_readlane((int)(unsigned)(v >> 32), i);
    return ((unsigned long long)hi << 32) | (unsigned long long)lo;
}

// Greedy NMS scan:
//  - ALL 4 waves run the resolve redundantly (identical inputs => identical results).
//  - SUPPRESSOR-SKIP resolve: rowR[l] only has bits > l, so
//    Z = ballot(live && (rowR & pend)) is exactly the set of lanes that can
//    change the outcome; the scalar chain visits only Z (typically 0-3 lanes).
//  - Tcol row loads for tile g+1 issued while tile g is merged (latency hidden).
//  - partial[] double-buffered => ONE barrier per tile.
__global__ void k_nms_out(const float* __restrict__ sboxes, const unsigned long long* __restrict__ vwords,
                          const unsigned long long* __restrict__ diagR, const unsigned* __restrict__ Tcol,
                          float* __restrict__ out){
    __shared__ unsigned long long keepw[24];
    __shared__ unsigned partial[2][4][64];
    int t = threadIdx.x;
    int wv = t >> 6, lane = t & 63;
    unsigned SS = 0u;      // bit g = box g*64+lane suppressed; identical in all waves
    unsigned long long rowR = diagR[lane];
    unsigned long long vcur = vwords[0];
    unsigned rows[16];
    {
        const unsigned* b0 = Tcol + (size_t)(wv*16)*64 + lane;
        #pragma unroll
        for (int i=0;i<16;i++) rows[i] = b0[i*64];
    }
    for (int g = 0; g < 24; g++){
        unsigned long long Rnext = (g < 23) ? diagR[(g+1)*64 + lane] : 0ull;
        unsigned long long vnext = (g < 23) ? vwords[g+1] : 0ull;
        bool live = (((vcur >> lane) & 1ull) != 0ull) && (((SS >> g) & 1u) == 0u);
        unsigned long long pend = __ballot(live);
        unsigned long long Z = __ballot(live && ((rowR & pend) != 0ull));
        unsigned long long kept = pend;
        unsigned long long iter = Z;
        while (iter){
            int i = __ffsll((long long)iter) - 1;
            iter &= iter - 1ull;
            if ((kept >> i) & 1ull){
                unsigned long long sup = readlane64(rowR, i);   // only bits > i
                kept &= ~sup;
                iter &= ~sup;
            }
        }
        if (t == 0) keepw[g] = kept;
        unsigned kbits = (unsigned)((kept >> (wv*16)) & 0xFFFFull);   // wave-uniform
        unsigned acc = 0u;
        #pragma unroll
        for (int i=0;i<16;i++) acc |= (0u - ((kbits >> i) & 1u)) & rows[i];
        if (g < 23){
            const unsigned* nb = Tcol + (size_t)((g+1)*64 + wv*16)*64 + lane;
            #pragma unroll
            for (int i=0;i<16;i++) rows[i] = nb[i*64];
        }
        partial[g & 1][wv][lane] = acc;
        __syncthreads();
        SS |= partial[g & 1][0][lane] | partial[g & 1][1][lane]
            | partial[g & 1][2][lane] | partial[g & 1][3][lane];
        rowR = Rnext; vcur = vnext;
    }
    for (int e=t; e<NBOX*9; e+=256){
        int r = e / 9;
        int c = e - r*9;
        bool kp = ((keepw[r >> 6] >> (r & 63)) & 1ull) != 0ull;
        out[e] = kp ? sboxes[r*12 + c] : 0.f;
    }
}

extern "C" void kernel_launch(void* const* d_in, const int* in_sizes, int n_in,
                              void* d_out, int out_size, void* d_ws, size_t ws_size,
                              hipStream_t stream){
    const float* o13 = (const float*)d_in[0];
    const float* o26 = (const float*)d_in[1];
    const float* o52 = (const float*)d_in[2];
    const float* a13 = (const float*)d_in[3];
    const float* a26 = (const float*)d_in[4];
    const float* a52 = (const float*)d_in[5];
    char* ws = (char*)d_ws;
    unsigned* scr             = (unsigned*)(ws);                        // TOTCELL*4 = 1,362,816
    unsigned* Tcol            = (unsigned*)(ws);                        // 393,216 — ALIASES scr (scr dead after k_classify)
    int* hist                 = (int*)(ws + 1362816);                   // 12,288
    int* cnt                  = (int*)(ws + 1375104);                   // 128
    unsigned long long* above = (unsigned long long*)(ws + 1375232);    // 12,288
    unsigned long long* sel   = (unsigned long long*)(ws + 1387520);    // 12,288
    unsigned long long* stash = (unsigned long long*)(ws + 1399808);    // 24,576
    float* sboxes             = (float*)(ws + 1424384);                 // 73,728
    unsigned long long* vw    = (unsigned long long*)(ws + 1498112);    // 256
    unsigned long long* diagR = (unsigned long long*)(ws + 1498368);    // 12,288 (end ~1.51 MB)
    float* out = (float*)d_out;

    k_init        <<<12, 256, 0, stream>>>(hist, cnt);
    k_score       <<<(TOTCELL + 255)/256, 256, 0, stream>>>(o13, o26, o52, scr, hist);
    k_cutoff      <<<3, NBINS, 0, stream>>>(hist, cnt);
    k_classify    <<<(TOTCELL/4 + 255)/256, 256, 0, stream>>>(scr, cnt, above, stash);
    k_finalize    <<<3, 1024, 0, stream>>>(cnt, above, stash, sel);
    k_decode_merge<<<NBOX/4, 256, 0, stream>>>(o13, o26, o52, a13, a26, a52, sel, cnt, sboxes, vw);
    k_masks       <<<NBOX, 64, 0, stream>>>(sboxes, Tcol, diagR);
    k_nms_out     <<<1, 256, 0, stream>>>(sboxes, vw, diagR, Tcol, out);
}

// Round 6
// 230.823 us; speedup vs baseline: 1.0769x; 1.0769x over previous
//
#include <hip/hip_runtime.h>
#include <stdint.h>

#define KPS 512
#define NBOX 1536
#define NBINS 1024
#define CAP 96          // bucket capacity; bins >= cutoff hold <= ~30 keys (3x margin)

// scale cell counts: 32*H*H*3
#define S13 16224
#define S26 64896
#define S52 259584
#define TOTCELL 340704

__device__ __forceinline__ uint32_t f2u(float x){ union{float f;uint32_t u;}v; v.f=x; return v.u; }
__device__ __forceinline__ float u2f(uint32_t x){ union{float f;uint32_t u;}v; v.u=x; return v.f; }

__device__ __forceinline__ int binOf(float s){
    int b = (int)((s - 0.6f) * 2560.0f);    // 1024 bins over (0.6, 1.0)
    if (b < 0) b = 0;
    if (b > NBINS-1) b = NBINS-1;
    return b;
}

__global__ void k_init(int* hist){
    int id = blockIdx.x*256 + threadIdx.x;
    if (id < 3*NBINS) hist[id] = 0;
}

// Score + direct bucket binning: the hist atomicAdd doubles as the bucket
// cursor (hist keeps TRUE counts even when writes clamp at CAP). Bins >= the
// eventual cutoff never clamp (suffix(B+1) < 512 and boundary bin ~30 keys).
__global__ void k_score(const float* __restrict__ o13, const float* __restrict__ o26,
                        const float* __restrict__ o52,
                        unsigned long long* __restrict__ bucket, int* __restrict__ hist){
    int id = blockIdx.x*256 + threadIdx.x;
    if (id >= TOTCELL) return;
    int scale, idl, H;
    const float* src;
    if (id < S13)            { scale=0; idl=id;            H=13; src=o13; }
    else if (id < S13+S26)   { scale=1; idl=id-S13;        H=26; src=o26; }
    else                     { scale=2; idl=id-(S13+S26);  H=52; src=o52; }
    int HW = H*H;
    // plane-major thread mapping for coalescing: idl = p*HW + hw, p = n*3 + a
    int p  = idl / HW;
    int hw = idl - p*HW;
    int n  = p / 3;
    int a  = p - n*3;
    float x = src[(size_t)(n*255 + a*85)*HW + hw];
    float s = (float)(1.0 / (1.0 + exp(-(double)x)));   // correctly-rounded f32 sigmoid
    if (s > 0.6f){
        int cidx = (n*HW + hw)*3 + a;       // reference flat cell index
        unsigned long long key = ((unsigned long long)f2u(s) << 20)
            | ((unsigned long long)(2-scale) << 18)
            | (unsigned long long)(262143 - cidx);
        int slot = scale*NBINS + binOf(s);
        int pos = atomicAdd(&hist[slot], 1);
        if (pos < CAP) bucket[(size_t)slot*CAP + pos] = key;
    }
}

// Fused cutoff+gather+rank-sort: one block per scale.
//  - suffix scan of hist -> cutoff bin B (same definition as always)
//  - gather all keys in bins >= B (<= 511 + ~30 keys) using suffix counts as
//    exact offsets (no clamping occurs in these bins)
//  - rank-sort (keys unique & nonzero) -> sel sorted desc + zero sentinels.
//  Equivalence: bin is monotone in key high bits, so top-Nsel of the union ==
//  (all bins > B) + top-(512-A) of bin B — the verified R5 selection.
__global__ void __launch_bounds__(1024) k_selfin(const int* __restrict__ hist,
                        const unsigned long long* __restrict__ bucket,
                        unsigned long long* __restrict__ sel, int* __restrict__ cnt){
    int s = blockIdx.x, t = threadIdx.x;
    __shared__ int suf[NBINS];
    __shared__ unsigned long long un[640];      // <= 511 + CAP
    __shared__ int sB;
    int h = hist[s*NBINS + t];
    suf[t] = h; __syncthreads();
    for (int d = 1; d < NBINS; d <<= 1){        // in-place suffix scan
        int v = (t + d < NBINS) ? suf[t + d] : 0;
        __syncthreads();
        suf[t] += v;
        __syncthreads();
    }
    int total = suf[0];
    int A = (t < NBINS-1) ? suf[t+1] : 0;       // count strictly above bin t
    if (t == 0 && total < KPS) sB = -1;
    if (A < KPS && A + h >= KPS) sB = t;        // unique crossing when total>=KPS
    __syncthreads();
    int B = sB;
    int Bg = (B < 0) ? 0 : B;
    // gather: thread t handles bin Bg+t; offset of bin b = suffix(b+1)
    if (t + Bg < NBINS){
        int b = Bg + t;
        int cb = hist[s*NBINS + b]; if (cb > CAP) cb = CAP;
        int off = (b == NBINS-1) ? 0 : suf[b+1];
        for (int e = 0; e < cb; e++)
            un[off + e] = bucket[(size_t)(s*NBINS + b)*CAP + e];
    }
    __syncthreads();
    int hB = hist[s*NBINS + Bg]; if (hB > CAP) hB = CAP;
    int E = ((Bg == NBINS-1) ? 0 : suf[Bg+1]) + hB;   // gathered count
    int Nsel = (E < KPS) ? E : KPS;
    for (int e = t; e < E; e += 1024){
        unsigned long long k = un[e];
        int rank = 0;
        for (int q = 0; q < E; q++) rank += (un[q] > k) ? 1 : 0;
        if (rank < Nsel) sel[s*KPS + rank] = k;
    }
    if (t < KPS && t >= Nsel) sel[s*KPS + t] = 0ull;   // sentinels
    if (t == 0) cnt[s] = Nsel;
}

// Fused decode+merge: stage all sel keys in LDS, compute each box's global rank
// (wave scan + shuffle reduce; keys unique, zeros tie-broken by position),
// decode, and write straight to sboxes[rank]. Block 0 emits analytic vwords.
__global__ void k_decode_merge(const float* __restrict__ o13, const float* __restrict__ o26,
                         const float* __restrict__ o52,
                         const float* __restrict__ a13, const float* __restrict__ a26,
                         const float* __restrict__ a52,
                         const unsigned long long* __restrict__ sel, const int* __restrict__ cnt,
                         float* __restrict__ sboxes, unsigned long long* __restrict__ vwords){
    __shared__ unsigned long long sk[NBOX];
    int t = threadIdx.x;
    for (int r = t; r < NBOX; r += 256) sk[r] = sel[r];
    __syncthreads();
    int wv = t >> 6, lane = t & 63;
    int b = blockIdx.x*4 + wv;
    unsigned long long key = sk[b];
    int pc = 0;
    for (int q = lane; q < NBOX; q += 64){
        unsigned long long kq = sk[q];
        pc += (kq > key || (kq == key && q < b)) ? 1 : 0;
    }
    #pragma unroll
    for (int off = 32; off; off >>= 1) pc += __shfl_xor(pc, off);
    int rank = pc;                       // permutation of [0,NBOX)
    float* row = sboxes + rank*12;
    if ((key >> 20) == 0ull){            // sentinel
        if (lane < 9) row[lane] = 0.f;
    } else {
        int scale = 2 - (int)((key >> 18) & 3ull);
        int cidx  = 262143 - (int)(key & 0x3FFFFull);
        uint32_t sbits = (uint32_t)(key >> 20);
        const float* src; const float* anch; int H; float tt;
        if (scale == 0){ src=o13; anch=a13; H=13; tt=32.f; }
        else if (scale == 1){ src=o26; anch=a26; H=26; tt=16.f; }
        else { src=o52; anch=a52; H=52; tt=8.f; }
        int HW = H*H;
        int a  = cidx % 3;
        int hw = (cidx/3) % HW;
        int n  = cidx / (3*HW);
        int hh = hw / H;
        int ww = hw - hh*H;
        const float* cellbase = src + (size_t)(n*255 + a*85)*HW + hw;
        // argmax over 80 classes, tie -> lowest class index
        float bv = cellbase[(size_t)(5 + lane)*HW];
        int bi = lane;
        if (lane < 16){
            float v2 = cellbase[(size_t)(69 + lane)*HW];
            if (v2 > bv){ bv = v2; bi = 64 + lane; }
        }
        #pragma unroll
        for (int off=32; off; off>>=1){
            float vo = __shfl_xor(bv, off);
            int io = __shfl_xor(bi, off);
            if (vo > bv || (vo == bv && io < bi)){ bv = vo; bi = io; }
        }
        if (lane == 0){
            float v1 = cellbase[(size_t)1*HW];
            float v2 = cellbase[(size_t)2*HW];
            float v3 = cellbase[(size_t)3*HW];
            float v4 = cellbase[(size_t)4*HW];
            float cx = ((float)ww + v1) * tt / 416.0f;
            float cy = ((float)hh + v2) * tt / 416.0f;
            float e3 = (float)exp((double)v3);
            float e4 = (float)exp((double)v4);
            float bw = anch[a*2+0] * e3 / 416.0f;
            float bh = anch[a*2+1] * e4 / 416.0f;
            row[0] = (float)n;  row[1] = cx; row[2] = cy; row[3] = bw; row[4] = bh;
            row[5] = u2f(sbits); row[6] = (float)bi; row[7] = (float)hh; row[8] = (float)ww;
        }
    }
    if (blockIdx.x == 0 && t < 24){
        int nv = cnt[0] + cnt[1] + cnt[2];   // valid keys sort to a contiguous prefix
        int rem = nv - t*64;
        vwords[t] = rem >= 64 ? ~0ull : (rem <= 0 ? 0ull : ((1ull << rem) - 1ull));
    }
}

// Column-sliced suppression matrix: Tcol[i*64 + j] bit c = sup(i, c*64+j).
// Diagonal-tile ROW masks: diagR[i] bit j = sup(i, gi*64+j) where gi = i>>6.
__global__ void k_masks(const float* __restrict__ sboxes, unsigned* __restrict__ Tcol,
                        unsigned long long* __restrict__ diagR){
    int i = blockIdx.x;
    int lane = threadIdx.x;
    int gi = i >> 6;
    float cxi = sboxes[i*12+1], cyi = sboxes[i*12+2], wi = sboxes[i*12+3], hi = sboxes[i*12+4];
    float x1i = cxi - wi/2.0f, y1i = cyi - hi/2.0f, x2i = cxi + wi/2.0f, y2i = cyi + hi/2.0f;
    float ari = fmaxf(x2i-x1i, 0.f) * fmaxf(y2i-y1i, 0.f);
    unsigned colbits = 0u;
    for (int c=0; c<24; c++){
        int j = c*64 + lane;
        float cxj = sboxes[j*12+1], cyj = sboxes[j*12+2], wj = sboxes[j*12+3], hj = sboxes[j*12+4];
        float x1j = cxj - wj/2.0f, y1j = cyj - hj/2.0f, x2j = cxj + wj/2.0f, y2j = cyj + hj/2.0f;
        float arj = fmaxf(x2j-x1j, 0.f) * fmaxf(y2j-y1j, 0.f);
        float ix = fmaxf(0.f, fminf(x2i, x2j) - fmaxf(x1i, x1j));
        float iy = fmaxf(0.f, fminf(y2i, y2j) - fmaxf(y1i, y1j));
        float inter = ix * iy;
        float iou = inter / fmaxf(fminf(ari, arj), 1e-9f);
        bool sb = (iou > 0.7f) && (j > i);
        colbits |= sb ? (1u << c) : 0u;
    }
    Tcol[(size_t)i*64 + lane] = colbits;
    unsigned long long rowbits = __ballot(((colbits >> gi) & 1u) != 0u);
    if (lane == 0) diagR[i] = rowbits;
}

__device__ __forceinline__ unsigned long long readlane64(unsigned long long v, int i){
    unsigned lo = (unsigned)__builtin_amdgcn_readlane((int)(unsigned)v, i);
    unsigned hi = (unsigned)__builtin_amdgcn_readlane((int)(unsigned)(v >> 32), i);
    return ((unsigned long long)hi << 32) | (unsigned long long)lo;
}

// Greedy NMS scan:
//  - ALL 4 waves run the resolve redundantly (identical inputs => identical results).
//  - SUPPRESSOR-SKIP resolve: rowR[l] only has bits > l, so
//    Z = ballot(live && (rowR & pend)) is exactly the set of lanes that can
//    change the outcome; the scalar chain visits only Z (typically 0-3 lanes).
//  - Tcol row loads for tile g+1 issued while tile g is merged (latency hidden).
//  - partial[] double-buffered => ONE barrier per tile.
__global__ void k_nms_out(const float* __restrict__ sboxes, const unsigned long long* __restrict__ vwords,
                          const unsigned long long* __restrict__ diagR, const unsigned* __restrict__ Tcol,
                          float* __restrict__ out){
    __shared__ unsigned long long keepw[24];
    __shared__ unsigned partial[2][4][64];
    int t = threadIdx.x;
    int wv = t >> 6, lane = t & 63;
    unsigned SS = 0u;      // bit g = box g*64+lane suppressed; identical in all waves
    unsigned long long rowR = diagR[lane];
    unsigned long long vcur = vwords[0];
    unsigned rows[16];
    {
        const unsigned* b0 = Tcol + (size_t)(wv*16)*64 + lane;
        #pragma unroll
        for (int i=0;i<16;i++) rows[i] = b0[i*64];
    }
    for (int g = 0; g < 24; g++){
        unsigned long long Rnext = (g < 23) ? diagR[(g+1)*64 + lane] : 0ull;
        unsigned long long vnext = (g < 23) ? vwords[g+1] : 0ull;
        bool live = (((vcur >> lane) & 1ull) != 0ull) && (((SS >> g) & 1u) == 0u);
        unsigned long long pend = __ballot(live);
        unsigned long long Z = __ballot(live && ((rowR & pend) != 0ull));
        unsigned long long kept = pend;
        unsigned long long iter = Z;
        while (iter){
            int i = __ffsll((long long)iter) - 1;
            iter &= iter - 1ull;
            if ((kept >> i) & 1ull){
                unsigned long long sup = readlane64(rowR, i);   // only bits > i
                kept &= ~sup;
                iter &= ~sup;
            }
        }
        if (t == 0) keepw[g] = kept;
        unsigned kbits = (unsigned)((kept >> (wv*16)) & 0xFFFFull);   // wave-uniform
        unsigned acc = 0u;
        #pragma unroll
        for (int i=0;i<16;i++) acc |= (0u - ((kbits >> i) & 1u)) & rows[i];
        if (g < 23){
            const unsigned* nb = Tcol + (size_t)((g+1)*64 + wv*16)*64 + lane;
            #pragma unroll
            for (int i=0;i<16;i++) rows[i] = nb[i*64];
        }
        partial[g & 1][wv][lane] = acc;
        __syncthreads();
        SS |= partial[g & 1][0][lane] | partial[g & 1][1][lane]
            | partial[g & 1][2][lane] | partial[g & 1][3][lane];
        rowR = Rnext; vcur = vnext;
    }
    for (int e=t; e<NBOX*9; e+=256){
        int r = e / 9;
        int c = e - r*9;
        bool kp = ((keepw[r >> 6] >> (r & 63)) & 1ull) != 0ull;
        out[e] = kp ? sboxes[r*12 + c] : 0.f;
    }
}

extern "C" void kernel_launch(void* const* d_in, const int* in_sizes, int n_in,
                              void* d_out, int out_size, void* d_ws, size_t ws_size,
                              hipStream_t stream){
    const float* o13 = (const float*)d_in[0];
    const float* o26 = (const float*)d_in[1];
    const float* o52 = (const float*)d_in[2];
    const float* a13 = (const float*)d_in[3];
    const float* a26 = (const float*)d_in[4];
    const float* a52 = (const float*)d_in[5];
    char* ws = (char*)d_ws;
    unsigned long long* bucket = (unsigned long long*)(ws);             // 3*1024*96*8 = 2,359,296
    unsigned* Tcol            = (unsigned*)(ws);                        // 393,216 — ALIASES bucket (dead after k_selfin)
    int* hist                 = (int*)(ws + 2359296);                   // 12,288
    int* cnt                  = (int*)(ws + 2371584);                   // 128
    unsigned long long* sel   = (unsigned long long*)(ws + 2371712);    // 12,288
    float* sboxes             = (float*)(ws + 2384000);                 // 73,728
    unsigned long long* vw    = (unsigned long long*)(ws + 2457728);    // 256
    unsigned long long* diagR = (unsigned long long*)(ws + 2457984);    // 12,288 (end ~2.47 MB)
    float* out = (float*)d_out;

    k_init        <<<12, 256, 0, stream>>>(hist);
    k_score       <<<(TOTCELL + 255)/256, 256, 0, stream>>>(o13, o26, o52, bucket, hist);
    k_selfin      <<<3, 1024, 0, stream>>>(hist, bucket, sel, cnt);
    k_decode_merge<<<NBOX/4, 256, 0, stream>>>(o13, o26, o52, a13, a26, a52, sel, cnt, sboxes, vw);
    k_masks       <<<NBOX, 64, 0, stream>>>(sboxes, Tcol, diagR);
    k_nms_out     <<<1, 256, 0, stream>>>(sboxes, vw, diagR, Tcol, out);
}